// Round 1
// baseline (439.783 us; speedup 1.0000x reference)
//
#include <hip/hip_runtime.h>

static constexpr float HS3 = 0.35355339059327373f; // (1/sqrt(2))^3

// s[m], m = sz*4 + sy*2 + sx (subband bits); o[p], p = pz*4 + py*2 + px (parity bits)
// o[p] = HS3 * sum_m s[m] * (-1)^(popcount(m & p))
__device__ __forceinline__ void ihaar8(const float s[8], float o[8]) {
    float ex[8]; // x butterfly
#pragma unroll
    for (int m = 0; m < 8; m += 2) { ex[m] = s[m] + s[m + 1]; ex[m + 1] = s[m] - s[m + 1]; }
    float ey[8]; // y butterfly
#pragma unroll
    for (int i = 0; i < 2; ++i)
#pragma unroll
        for (int px = 0; px < 2; ++px) {
            ey[i * 4 + 0 + px] = ex[i * 4 + 0 + px] + ex[i * 4 + 2 + px];
            ey[i * 4 + 2 + px] = ex[i * 4 + 0 + px] - ex[i * 4 + 2 + px];
        }
#pragma unroll
    for (int q = 0; q < 4; ++q) { // z butterfly + scale
        o[q]     = (ey[q] + ey[4 + q]) * HS3;
        o[4 + q] = (ey[q] - ey[4 + q]) * HS3;
    }
}

// Levels 0/1: A [8][R][R][R], det [7][8][R][R][R] -> out [8][2R][2R][2R] (c-major)
__global__ void idwt_pass(const float* __restrict__ A, const float* __restrict__ det,
                          float* __restrict__ out, int R) {
    int tid = blockIdx.x * blockDim.x + threadIdx.x;
    int R3 = R * R * R;
    if (tid >= 8 * R3) return;
    int c = tid / R3;
    int rem = tid - c * R3;
    int Z = rem / (R * R);
    int r2 = rem - Z * (R * R);
    int Y = r2 / R;
    int X = r2 - Y * R;

    float s[8];
    s[0] = A[tid];
    const float* dp = det + (size_t)c * R3 + rem;
    size_t bs = (size_t)8 * R3;
#pragma unroll
    for (int b = 0; b < 7; ++b) s[b + 1] = dp[(size_t)b * bs];

    float o[8];
    ihaar8(s, o);

    int Ro = 2 * R;
    float2* out2 = reinterpret_cast<float2*>(out);
#pragma unroll
    for (int pz = 0; pz < 2; ++pz)
#pragma unroll
        for (int py = 0; py < 2; ++py) {
            size_t idx = ((size_t)(c * Ro + 2 * Z + pz) * Ro + (2 * Y + py)) * R + X; // float2 index
            out2[idx] = make_float2(o[pz * 4 + py * 2 + 0], o[pz * 4 + py * 2 + 1]);
        }
}

// Level 2: A = vol2 [8][128][128][128] (c-major), det = detail2 [7][8][128^3]
// -> out channel-last [256][256][256][8]
__global__ void idwt_passC(const float* __restrict__ A, const float* __restrict__ det,
                           float* __restrict__ out) {
    const int R = 128;
    const int R3 = R * R * R;
    int tid = blockIdx.x * blockDim.x + threadIdx.x;
    if (tid >= R3) return;
    int Z = tid / (R * R);
    int r2 = tid - Z * (R * R);
    int Y = r2 / R;
    int X = r2 - Y * R;

    float ob[8][8]; // [parity p][channel c]
#pragma unroll
    for (int c = 0; c < 8; ++c) {
        float s[8];
        s[0] = A[(size_t)c * R3 + tid];
        const float* dp = det + (size_t)c * R3 + tid;
#pragma unroll
        for (int b = 0; b < 7; ++b) s[b + 1] = dp[(size_t)(b * 8) * R3];
        float o[8];
        ihaar8(s, o);
#pragma unroll
        for (int p = 0; p < 8; ++p) ob[p][c] = o[p];
    }

    const int Ro = 256;
    float4* out4 = reinterpret_cast<float4*>(out);
#pragma unroll
    for (int pz = 0; pz < 2; ++pz)
#pragma unroll
        for (int py = 0; py < 2; ++py)
#pragma unroll
            for (int px = 0; px < 2; ++px) {
                int p = pz * 4 + py * 2 + px;
                size_t e = (((size_t)(2 * Z + pz) * Ro + (2 * Y + py)) * Ro + (2 * X + px)) * 2;
                out4[e]     = make_float4(ob[p][0], ob[p][1], ob[p][2], ob[p][3]);
                out4[e + 1] = make_float4(ob[p][4], ob[p][5], ob[p][6], ob[p][7]);
            }
}

__device__ __forceinline__ float map_grid(float v) {
    float g = (v * (1.0f / 1.5f) + 1.0f) * (0.5f * 255.0f);
    return fminf(fmaxf(g, 0.0f), 255.0f);
}

__global__ void sample_kernel(const float* __restrict__ xyz, const float* __restrict__ vol,
                              float* __restrict__ out, int N) {
    int i = blockIdx.x * blockDim.x + threadIdx.x;
    if (i >= N) return;
    float gx = map_grid(xyz[3 * i + 0]);
    float gy = map_grid(xyz[3 * i + 1]);
    float gz = map_grid(xyz[3 * i + 2]);
    float x0f = floorf(gx), y0f = floorf(gy), z0f = floorf(gz);
    int x0 = (int)x0f, y0 = (int)y0f, z0 = (int)z0f;
    float fx = gx - x0f, fy = gy - y0f, fz = gz - z0f;
    int x1 = min(x0 + 1, 255), y1 = min(y0 + 1, 255), z1 = min(z0 + 1, 255);
    float wx0 = 1.0f - fx, wy0 = 1.0f - fy, wz0 = 1.0f - fz;

    float acc[8];
#pragma unroll
    for (int k = 0; k < 8; ++k) acc[k] = 0.0f;

    auto corner = [&](int z, int y, int x, float w) {
        const float4* v4 = reinterpret_cast<const float4*>(vol + ((((size_t)z * 256 + y) * 256 + x) << 3));
        float4 a = v4[0], b = v4[1];
        acc[0] += w * a.x; acc[1] += w * a.y; acc[2] += w * a.z; acc[3] += w * a.w;
        acc[4] += w * b.x; acc[5] += w * b.y; acc[6] += w * b.z; acc[7] += w * b.w;
    };
    corner(z0, y0, x0, wz0 * wy0 * wx0);
    corner(z0, y0, x1, wz0 * wy0 * fx);
    corner(z0, y1, x0, wz0 * fy * wx0);
    corner(z0, y1, x1, wz0 * fy * fx);
    corner(z1, y0, x0, fz * wy0 * wx0);
    corner(z1, y0, x1, fz * wy0 * fx);
    corner(z1, y1, x0, fz * fy * wx0);
    corner(z1, y1, x1, fz * fy * fx);

    float4* o4 = reinterpret_cast<float4*>(out + (size_t)i * 8);
    o4[0] = make_float4(acc[0], acc[1], acc[2], acc[3]);
    o4[1] = make_float4(acc[4], acc[5], acc[6], acc[7]);
}

extern "C" void kernel_launch(void* const* d_in, const int* in_sizes, int n_in,
                              void* d_out, int out_size, void* d_ws, size_t ws_size,
                              hipStream_t stream) {
    const float* xyz     = (const float*)d_in[0];
    const float* approx  = (const float*)d_in[1];
    const float* detail0 = (const float*)d_in[2];
    const float* detail1 = (const float*)d_in[3];
    const float* detail2 = (const float*)d_in[4];
    float* out = (float*)d_out;
    int N = in_sizes[0] / 3;

    char* ws = (char*)d_ws;
    float* vol1 = (float*)ws;                                   // 8*64^3  floats =   8 MiB
    float* vol2 = (float*)(ws + (size_t)8 * 1024 * 1024);       // 8*128^3 floats =  64 MiB
    float* vol3 = (float*)(ws + (size_t)72 * 1024 * 1024);      // 256^3*8 floats = 512 MiB (channel-last)

    // Level 0: 32 -> 64
    {
        int total = 8 * 32 * 32 * 32;
        idwt_pass<<<(total + 255) / 256, 256, 0, stream>>>(approx, detail0, vol1, 32);
    }
    // Level 1: 64 -> 128
    {
        int total = 8 * 64 * 64 * 64;
        idwt_pass<<<(total + 255) / 256, 256, 0, stream>>>(vol1, detail1, vol2, 64);
    }
    // Level 2: 128 -> 256 (channel-last output)
    {
        int total = 128 * 128 * 128;
        idwt_passC<<<(total + 255) / 256, 256, 0, stream>>>(vol2, detail2, vol3);
    }
    // Trilinear sampling
    sample_kernel<<<(N + 255) / 256, 256, 0, stream>>>(xyz, vol3, out, N);
}

// Round 2
// 286.793 us; speedup vs baseline: 1.5334x; 1.5334x over previous
//
#include <hip/hip_runtime.h>

static constexpr float HS3 = 0.35355339059327373f; // (1/sqrt(2))^3

// s[m], m = sz*4 + sy*2 + sx (subband bits); o[p], p = pz*4 + py*2 + px
__device__ __forceinline__ void ihaar8(const float s[8], float o[8]) {
    float ex[8];
#pragma unroll
    for (int m = 0; m < 8; m += 2) { ex[m] = s[m] + s[m + 1]; ex[m + 1] = s[m] - s[m + 1]; }
    float ey[8];
#pragma unroll
    for (int i = 0; i < 2; ++i)
#pragma unroll
        for (int px = 0; px < 2; ++px) {
            ey[i * 4 + 0 + px] = ex[i * 4 + 0 + px] + ex[i * 4 + 2 + px];
            ey[i * 4 + 2 + px] = ex[i * 4 + 0 + px] - ex[i * 4 + 2 + px];
        }
#pragma unroll
    for (int q = 0; q < 4; ++q) {
        o[q]     = (ey[q] + ey[4 + q]) * HS3;
        o[4 + q] = (ey[q] - ey[4 + q]) * HS3;
    }
}

__device__ __forceinline__ unsigned short f2bf(float f) {
    unsigned int u = __float_as_uint(f);
    unsigned int r = (u + 0x7FFFu + ((u >> 16) & 1u)) >> 16; // RNE
    return (unsigned short)r;
}

// Levels 0/1: A [8][R][R][R], det [7][8][R][R][R] -> out [8][2R][2R][2R] (c-major, f32)
__global__ void idwt_pass(const float* __restrict__ A, const float* __restrict__ det,
                          float* __restrict__ out, int R) {
    int tid = blockIdx.x * blockDim.x + threadIdx.x;
    int R3 = R * R * R;
    if (tid >= 8 * R3) return;
    int c = tid / R3;
    int rem = tid - c * R3;
    int Z = rem / (R * R);
    int r2 = rem - Z * (R * R);
    int Y = r2 / R;
    int X = r2 - Y * R;

    float s[8];
    s[0] = A[tid];
    const float* dp = det + (size_t)c * R3 + rem;
    size_t bs = (size_t)8 * R3;
#pragma unroll
    for (int b = 0; b < 7; ++b) s[b + 1] = dp[(size_t)b * bs];

    float o[8];
    ihaar8(s, o);

    int Ro = 2 * R;
    float2* out2 = reinterpret_cast<float2*>(out);
#pragma unroll
    for (int pz = 0; pz < 2; ++pz)
#pragma unroll
        for (int py = 0; py < 2; ++py) {
            size_t idx = ((size_t)(c * Ro + 2 * Z + pz) * Ro + (2 * Y + py)) * R + X;
            out2[idx] = make_float2(o[pz * 4 + py * 2 + 0], o[pz * 4 + py * 2 + 1]);
        }
}

// Level 2: vol2 [8][128^3] f32 + detail2 [7][8][128^3] f32 -> vol3 channel-last bf16 [256][256][256][8]
// Block: 512 threads, tile = 256 consecutive cells. LDS-staged cooperative loads:
// one wave instruction reads 1 KiB contiguous from ONE stream (64 lanes x float4).
__global__ __launch_bounds__(512) void idwt_passC2(const float* __restrict__ A,
                                                   const float* __restrict__ det,
                                                   unsigned short* __restrict__ out) {
    const int R3 = 128 * 128 * 128;
    __shared__ float4 lds4[64][64]; // [stream][float4-chunk of 256-cell tile] = 64 KiB

    int T0 = blockIdx.x * 256; // cell base of this tile
    int t = threadIdx.x;
    int wave = t >> 6, lane = t & 63;

    // phase 1: 8 waves x 8 streams each; stream s: s<8 -> A channel s; else det (s-8) = b*8+c
#pragma unroll
    for (int k = 0; k < 8; ++k) {
        int s = wave * 8 + k;
        const float* base = (s < 8) ? (A + (size_t)s * R3) : (det + (size_t)(s - 8) * R3);
        const float4* src = reinterpret_cast<const float4*>(base) + (T0 >> 2);
        lds4[s][lane] = src[lane];
    }
    __syncthreads();

    // phase 2: 512 threads = 256 cells x 2 channel-halves
    int cell = t & 255;
    int h = t >> 8; // channels h*4 .. h*4+3
    int cid = T0 + cell;
    int Z = cid >> 14;
    int r2 = cid & 16383;
    int Y = r2 >> 7;
    int X = r2 & 127;

    const float* ld = reinterpret_cast<const float*>(&lds4[0][0]); // [s*256 + cell]

    float ob[8][4]; // [parity][cc]
#pragma unroll
    for (int cc = 0; cc < 4; ++cc) {
        int c = h * 4 + cc;
        float s8[8];
        s8[0] = ld[c * 256 + cell];
#pragma unroll
        for (int b = 0; b < 7; ++b) s8[b + 1] = ld[(8 + b * 8 + c) * 256 + cell];
        float o[8];
        ihaar8(s8, o);
#pragma unroll
        for (int p = 0; p < 8; ++p) ob[p][cc] = o[p];
    }

    // store: voxel = 8 bf16 = 16 B; this thread writes its 8 B half per parity
    uint2* out2 = reinterpret_cast<uint2*>(out);
#pragma unroll
    for (int pz = 0; pz < 2; ++pz)
#pragma unroll
        for (int py = 0; py < 2; ++py)
#pragma unroll
            for (int px = 0; px < 2; ++px) {
                int p = pz * 4 + py * 2 + px;
                size_t vox = (((size_t)(2 * Z + pz) * 256 + (2 * Y + py)) * 256 + (2 * X + px));
                uint2 v;
                v.x = (unsigned int)f2bf(ob[p][0]) | ((unsigned int)f2bf(ob[p][1]) << 16);
                v.y = (unsigned int)f2bf(ob[p][2]) | ((unsigned int)f2bf(ob[p][3]) << 16);
                out2[vox * 2 + h] = v;
            }
}

__device__ __forceinline__ float map_grid(float v) {
    float g = (v * (1.0f / 1.5f) + 1.0f) * (0.5f * 255.0f);
    return fminf(fmaxf(g, 0.0f), 255.0f);
}

__global__ void sample_kernel(const float* __restrict__ xyz, const unsigned short* __restrict__ vol,
                              float* __restrict__ out, int N) {
    int i = blockIdx.x * blockDim.x + threadIdx.x;
    if (i >= N) return;
    float gx = map_grid(xyz[3 * i + 0]);
    float gy = map_grid(xyz[3 * i + 1]);
    float gz = map_grid(xyz[3 * i + 2]);
    float x0f = floorf(gx), y0f = floorf(gy), z0f = floorf(gz);
    int x0 = (int)x0f, y0 = (int)y0f, z0 = (int)z0f;
    float fx = gx - x0f, fy = gy - y0f, fz = gz - z0f;
    int x1 = min(x0 + 1, 255), y1 = min(y0 + 1, 255), z1 = min(z0 + 1, 255);
    float wx0 = 1.0f - fx, wy0 = 1.0f - fy, wz0 = 1.0f - fz;

    float acc[8];
#pragma unroll
    for (int k = 0; k < 8; ++k) acc[k] = 0.0f;

    auto corner = [&](int z, int y, int x, float w) {
        const uint4* v4 = reinterpret_cast<const uint4*>(vol + ((((size_t)z * 256 + y) * 256 + x) << 3));
        uint4 a = *v4; // 8 bf16
        acc[0] += w * __uint_as_float(a.x << 16);
        acc[1] += w * __uint_as_float(a.x & 0xFFFF0000u);
        acc[2] += w * __uint_as_float(a.y << 16);
        acc[3] += w * __uint_as_float(a.y & 0xFFFF0000u);
        acc[4] += w * __uint_as_float(a.z << 16);
        acc[5] += w * __uint_as_float(a.z & 0xFFFF0000u);
        acc[6] += w * __uint_as_float(a.w << 16);
        acc[7] += w * __uint_as_float(a.w & 0xFFFF0000u);
    };
    corner(z0, y0, x0, wz0 * wy0 * wx0);
    corner(z0, y0, x1, wz0 * wy0 * fx);
    corner(z0, y1, x0, wz0 * fy * wx0);
    corner(z0, y1, x1, wz0 * fy * fx);
    corner(z1, y0, x0, fz * wy0 * wx0);
    corner(z1, y0, x1, fz * wy0 * fx);
    corner(z1, y1, x0, fz * fy * wx0);
    corner(z1, y1, x1, fz * fy * fx);

    float4* o4 = reinterpret_cast<float4*>(out + (size_t)i * 8);
    o4[0] = make_float4(acc[0], acc[1], acc[2], acc[3]);
    o4[1] = make_float4(acc[4], acc[5], acc[6], acc[7]);
}

extern "C" void kernel_launch(void* const* d_in, const int* in_sizes, int n_in,
                              void* d_out, int out_size, void* d_ws, size_t ws_size,
                              hipStream_t stream) {
    const float* xyz     = (const float*)d_in[0];
    const float* approx  = (const float*)d_in[1];
    const float* detail0 = (const float*)d_in[2];
    const float* detail1 = (const float*)d_in[3];
    const float* detail2 = (const float*)d_in[4];
    float* out = (float*)d_out;
    int N = in_sizes[0] / 3;

    char* ws = (char*)d_ws;
    float* vol1 = (float*)ws;                                    // 8*64^3  f32 =   8 MiB
    float* vol2 = (float*)(ws + (size_t)8 * 1024 * 1024);        // 8*128^3 f32 =  64 MiB
    unsigned short* vol3 = (unsigned short*)(ws + (size_t)72 * 1024 * 1024); // 256^3*8 bf16 = 256 MiB

    // Level 0: 32 -> 64
    {
        int total = 8 * 32 * 32 * 32;
        idwt_pass<<<(total + 255) / 256, 256, 0, stream>>>(approx, detail0, vol1, 32);
    }
    // Level 1: 64 -> 128
    {
        int total = 8 * 64 * 64 * 64;
        idwt_pass<<<(total + 255) / 256, 256, 0, stream>>>(vol1, detail1, vol2, 64);
    }
    // Level 2: 128 -> 256, channel-last bf16, LDS-staged burst loads
    {
        int blocks = (128 * 128 * 128) / 256; // 8192
        idwt_passC2<<<blocks, 512, 0, stream>>>(vol2, detail2, vol3);
    }
    // Trilinear sampling from bf16 channel-last volume
    sample_kernel<<<(N + 255) / 256, 256, 0, stream>>>(xyz, vol3, out, N);
}